// Round 11
// baseline (149.553 us; speedup 1.0000x reference)
//
#include <hip/hip_runtime.h>
#include <stdint.h>

typedef __attribute__((ext_vector_type(8))) short short8;
typedef __attribute__((ext_vector_type(4))) float f32x4;
typedef __attribute__((ext_vector_type(16))) float f32x16;
typedef __attribute__((ext_vector_type(4))) unsigned short ushort4v;
typedef __attribute__((ext_vector_type(2))) unsigned int uint2v;

static __device__ __forceinline__ unsigned short f2b(float f) {
  union { float f; unsigned int u; } v; v.f = f;
  unsigned int r = v.u + 0x7FFFu + ((v.u >> 16) & 1u);
  return (unsigned short)(r >> 16);
}

static __device__ __forceinline__ float exp2fast(float x) {
#if __has_builtin(__builtin_amdgcn_exp2f)
  return __builtin_amdgcn_exp2f(x);
#else
  return exp2f(x);
#endif
}

static __device__ __forceinline__ unsigned int cvtpk(float lo, float hi) {
  unsigned int r;
  asm("v_cvt_pk_bf16_f32 %0, %1, %2" : "=v"(r) : "v"(lo), "v"(hi));
  return r;
}

static __device__ __forceinline__ float xor32max(float x) {
#if __has_builtin(__builtin_amdgcn_permlane32_swap)
  unsigned u = __float_as_uint(x);
  uint2v r = __builtin_amdgcn_permlane32_swap(u, u, false, false);
  return fmaxf(__uint_as_float(r[0]), __uint_as_float(r[1]));
#else
  return fmaxf(x, __shfl_xor(x, 32));
#endif
}
static __device__ __forceinline__ float xor32add(float x) {
#if __has_builtin(__builtin_amdgcn_permlane32_swap)
  unsigned u = __float_as_uint(x);
  uint2v r = __builtin_amdgcn_permlane32_swap(u, u, false, false);
  return __uint_as_float(r[0]) + __uint_as_float(r[1]);
#else
  return x + __shfl_xor(x, 32);
#endif
}

static __device__ __forceinline__ void gload16(const void* g, void* l) {
  __builtin_amdgcn_global_load_lds(
      (const __attribute__((address_space(1))) unsigned int*)g,
      (__attribute__((address_space(3))) unsigned int*)l, 16, 0, 0);
}

// ---------------- fused prep: cast_x | weight transpose | rope tables ----------------

__global__ __launch_bounds__(256) void prep_kernel(
    const float* __restrict__ x, const float* __restrict__ wq,
    const float* __restrict__ wk, const float* __restrict__ wv,
    const float* __restrict__ wo, unsigned short* __restrict__ xb,
    unsigned short* __restrict__ wT, float* __restrict__ ct,
    float* __restrict__ st) {
  __shared__ float t[32][33];
  const int bid = blockIdx.x, tid = threadIdx.x;
  if (bid < 4096) {  // cast x -> bf16
    int i = (bid * 256 + tid) * 4;
    float4 v = *(const float4*)(x + i);
    ushort4v o = { f2b(v.x), f2b(v.y), f2b(v.z), f2b(v.w) };
    *(ushort4v*)(xb + i) = o;
  } else if (bid < 8192) {  // transpose+cast weights
    int tt = bid - 4096;
    int z = tt >> 10, xy = tt & 1023;
    const float* src = (z == 0) ? wq : (z == 1) ? wk : (z == 2) ? wv : wo;
    unsigned short* dst = wT + (size_t)z * 1048576;
    int tx = tid & 31, ty = tid >> 5;
    int n0 = (xy & 31) * 32, k0 = (xy >> 5) * 32;
#pragma unroll
    for (int i = 0; i < 4; ++i) {
      int r = ty + i * 8;
      t[r][tx] = src[(size_t)(k0 + r) * 1024 + n0 + tx];
    }
    __syncthreads();
#pragma unroll
    for (int i = 0; i < 4; ++i) {
      int r = ty + i * 8;
      dst[(size_t)(n0 + r) * 1024 + k0 + tx] = f2b(t[tx][r]);
    }
  } else {  // rope tables (2048*32 entries)
    int i = (bid - 8192) * 256 + tid;
    int s = i >> 5, p = i & 31;
    float ang = (float)s * powf(10000.0f, -(float)(2 * p) / 64.0f);
    ct[i] = cosf(ang);
    st[i] = sinf(ang);
  }
}

// ---------------- QKV GEMM (A: MxK row-major bf16, Bt: NxK row-major bf16) ------------
// mode 0: Q epilogue (RoPE + fold 0.125*log2e, write (h,b,s,d)); mode 1: K epilogue;
// mode 2: V epilogue (write transposed (h,b,d,s)).

__global__ __launch_bounds__(256) void gemm_kernel(
    const unsigned short* __restrict__ A, const unsigned short* __restrict__ WT,
    unsigned short* __restrict__ Qb, unsigned short* __restrict__ Kb,
    unsigned short* __restrict__ VTb,
    const float* __restrict__ ctab, const float* __restrict__ stab) {
  __shared__ unsigned short As[128 * 32];
  __shared__ unsigned short Bs[128 * 32];
  const int tid = threadIdx.x;
  const int w = tid >> 6, lane = tid & 63;
  const int m0 = blockIdx.x * 128, n0 = blockIdx.y * 128;
  const int mode = blockIdx.z;
  const unsigned short* Bt = WT + (size_t)mode * 1048576;
  const int wr = w >> 1, wc = w & 1;
  const int srow = lane >> 2, scol = lane & 3;
  f32x4 acc[4][4] = {};
  for (int k0 = 0; k0 < 1024; k0 += 32) {
#pragma unroll
    for (int c = 0; c < 2; ++c) {
      int chunk = w * 2 + c;
      gload16(A + (size_t)(m0 + chunk * 16 + srow) * 1024 + k0 + scol * 8,
              (char*)As + chunk * 1024);
      gload16(Bt + (size_t)(n0 + chunk * 16 + srow) * 1024 + k0 + scol * 8,
              (char*)Bs + chunk * 1024);
    }
    __syncthreads();
    short8 af[4], bf[4];
#pragma unroll
    for (int i = 0; i < 4; ++i) {
      af[i] = *(const short8*)((const char*)As +
              ((wr * 64 + i * 16 + (lane & 15)) * 64 + (lane >> 4) * 16));
      bf[i] = *(const short8*)((const char*)Bs +
              ((wc * 64 + i * 16 + (lane & 15)) * 64 + (lane >> 4) * 16));
    }
#pragma unroll
    for (int i = 0; i < 4; ++i)
#pragma unroll
      for (int j = 0; j < 4; ++j)
        acc[i][j] = __builtin_amdgcn_mfma_f32_16x16x32_bf16(af[i], bf[j], acc[i][j], 0, 0, 0);
    __syncthreads();
  }

  if (mode < 2) {
    unsigned short* dst = mode ? Kb : Qb;
    const float qscale = mode ? 1.0f : 0.125f * 1.44269504088896f;
#pragma unroll
    for (int i = 0; i < 4; ++i) {
#pragma unroll
      for (int j = 0; j < 4; ++j) {
        int n = n0 + wc * 64 + j * 16 + (lane & 15);
        int h = n >> 6, d = n & 63;
        int pairIdx = d >> 1;
        bool even = (n & 1) == 0;
#pragma unroll
        for (int r = 0; r < 4; ++r) {
          int m = m0 + wr * 64 + i * 16 + (lane >> 4) * 4 + r;
          int b = m >> 11, s = m & 2047;
          float v = acc[i][j][r];
          float pv = __shfl_xor(v, 1);
          float c = ctab[s * 32 + pairIdx], sn = stab[s * 32 + pairIdx];
          float ov = (even ? (v * c - pv * sn) : (pv * sn + v * c)) * qscale;
          dst[(size_t)((h * 2 + b) * 2048 + s) * 64 + d] = f2b(ov);
        }
      }
    }
  } else {
#pragma unroll
    for (int i = 0; i < 4; ++i) {
#pragma unroll
      for (int j = 0; j < 4; ++j) {
        int n = n0 + wc * 64 + j * 16 + (lane & 15);
        int h = n >> 6, d = n & 63;
        int mBase = m0 + wr * 64 + i * 16 + (lane >> 4) * 4;
        int b = mBase >> 11, s = mBase & 2047;
        ushort4v pk = { f2b(acc[i][j][0]), f2b(acc[i][j][1]),
                        f2b(acc[i][j][2]), f2b(acc[i][j][3]) };
        *(ushort4v*)(VTb + (size_t)((h * 2 + b) * 64 + d) * 2048 + s) = pk;
      }
    }
  }
}

// ---------------- final GEMM: 64x128 tile, 2-wave blocks, fp32 out ----------------

__global__ __launch_bounds__(128) void gemm_final_kernel(
    const unsigned short* __restrict__ A, const unsigned short* __restrict__ Bt,
    float* __restrict__ Fout) {
  __shared__ unsigned short As[64 * 32];
  __shared__ unsigned short Bs[128 * 32];
  const int tid = threadIdx.x;
  const int w = tid >> 6, lane = tid & 63;
  const int m0 = blockIdx.x * 64, n0 = blockIdx.y * 128;
  const int srow = lane >> 2, scol = lane & 3;
  f32x4 acc[4][4] = {};
  for (int k0 = 0; k0 < 1024; k0 += 32) {
#pragma unroll
    for (int c = 0; c < 2; ++c) {
      int chunk = w * 2 + c;
      gload16(A + (size_t)(m0 + chunk * 16 + srow) * 1024 + k0 + scol * 8,
              (char*)As + chunk * 1024);
    }
#pragma unroll
    for (int c = 0; c < 4; ++c) {
      int chunk = w * 4 + c;
      gload16(Bt + (size_t)(n0 + chunk * 16 + srow) * 1024 + k0 + scol * 8,
              (char*)Bs + chunk * 1024);
    }
    __syncthreads();
    short8 af[4], bf[4];
#pragma unroll
    for (int i = 0; i < 4; ++i) {
      af[i] = *(const short8*)((const char*)As +
              ((i * 16 + (lane & 15)) * 64 + (lane >> 4) * 16));
      bf[i] = *(const short8*)((const char*)Bs +
              ((w * 64 + i * 16 + (lane & 15)) * 64 + (lane >> 4) * 16));
    }
#pragma unroll
    for (int i = 0; i < 4; ++i)
#pragma unroll
      for (int j = 0; j < 4; ++j)
        acc[i][j] = __builtin_amdgcn_mfma_f32_16x16x32_bf16(af[i], bf[j], acc[i][j], 0, 0, 0);
    __syncthreads();
  }
#pragma unroll
  for (int i = 0; i < 4; ++i)
#pragma unroll
    for (int j = 0; j < 4; ++j) {
      int n = n0 + w * 64 + j * 16 + (lane & 15);
#pragma unroll
      for (int r = 0; r < 4; ++r) {
        int m = m0 + i * 16 + (lane >> 4) * 4 + r;
        Fout[(size_t)m * 1024 + n] = acc[i][j][r];
      }
    }
}

// ---------------- causal flash attention, k-split x2 ----------------
// Job = (qt, hb, half). half0: kt in [0, qt+1); half1: kt in [qt+1, 2qt+2).
// Both halves = qt+1 tiles (equal work). Grid (32,32) = 1024 blocks -> 4 blocks/CU.
// NOTE: plain __launch_bounds__(256) -- r10's ",4" min-waves clause capped VGPR at 64
// and forced scratch spills (FETCH +16MB, WRITE +21MB, duration +9%). Natural VGPR
// (~116-130) still gives 4 waves/SIMD.

__global__ __launch_bounds__(256) void attn_kernel(
    const unsigned short* __restrict__ Qb, const unsigned short* __restrict__ Kb,
    const unsigned short* __restrict__ VTb, unsigned short* __restrict__ P0,
    unsigned short* __restrict__ P1, float* __restrict__ mls) {
  __shared__ unsigned short Ks[2][64 * 64];
  __shared__ unsigned short Vs[2][64 * 64];
  const int tid = threadIdx.x, w = tid >> 6, lane = tid & 63;
  const int lq = lane & 31, hi = lane >> 5;
  const int hb = blockIdx.y;
  const int half = blockIdx.x >> 4;
  const int i4 = blockIdx.x & 15;
  const int qt = (i4 < 8) ? i4 : 23 - i4;             // XCD-balanced bijection 0..15
  const int h = hb >> 1, b = hb & 1;
  const unsigned short* Qhb = Qb + (size_t)hb * 2048 * 64;
  const unsigned short* Khb = Kb + (size_t)hb * 2048 * 64;
  const unsigned short* Vhb = VTb + (size_t)hb * 64 * 2048;
  const int qbase = qt * 128 + w * 32;
  const int swq = (lq & 7) << 4;
  const int kt0 = half ? (qt + 1) : 0;
  const int ktend = half ? (2 * qt + 2) : (qt + 1);

  short8 qf[4];
#pragma unroll
  for (int s = 0; s < 4; ++s)
    qf[s] = *(const short8*)(Qhb + (size_t)(qbase + lq) * 64 + s * 16 + hi * 8);

  const f32x16 Z16 = {0,0,0,0,0,0,0,0,0,0,0,0,0,0,0,0};
  f32x16 o0 = Z16, o1 = Z16;
  float m = -__builtin_inff(), ls = 0.f;

  // staging: thread owns rows r0, r0+32 (16B each)
  const int r0 = tid >> 3, f0 = tid & 7;
  const int so0 = r0 * 128 + ((f0 * 16) ^ ((r0 & 7) << 4));
  short8 gK[2], gV[2];
  {
    int kk0 = kt0 * 64;
    gK[0] = *(const short8*)(Khb + (size_t)(kk0 + r0) * 64 + f0 * 8);
    gK[1] = *(const short8*)(Khb + (size_t)(kk0 + r0 + 32) * 64 + f0 * 8);
    gV[0] = *(const short8*)(Vhb + (size_t)r0 * 2048 + kk0 + f0 * 8);
    gV[1] = *(const short8*)(Vhb + (size_t)(r0 + 32) * 2048 + kk0 + f0 * 8);
  }
  *(short8*)((char*)Ks[0] + so0) = gK[0];
  *(short8*)((char*)Ks[0] + so0 + 32 * 128) = gK[1];
  *(short8*)((char*)Vs[0] + so0) = gV[0];
  *(short8*)((char*)Vs[0] + so0 + 32 * 128) = gV[1];
  __syncthreads();

  for (int kt = kt0; kt < ktend; ++kt) {
    const int cur = (kt - kt0) & 1;
    if (kt + 1 < ktend) {  // issue next tile's loads; latency hides under compute
      int kk0 = (kt + 1) * 64;
      gK[0] = *(const short8*)(Khb + (size_t)(kk0 + r0) * 64 + f0 * 8);
      gK[1] = *(const short8*)(Khb + (size_t)(kk0 + r0 + 32) * 64 + f0 * 8);
      gV[0] = *(const short8*)(Vhb + (size_t)r0 * 2048 + kk0 + f0 * 8);
      gV[1] = *(const short8*)(Vhb + (size_t)(r0 + 32) * 2048 + kk0 + f0 * 8);
    }
    if (kt * 64 <= qbase + 31) {  // wave has unmasked work in this tile
      const unsigned short* Ksb = Ks[cur];
      const unsigned short* Vsb = Vs[cur];
      f32x16 s0 = Z16, s1 = Z16;
      __builtin_amdgcn_s_setprio(1);
#pragma unroll
      for (int st = 0; st < 4; ++st) {
        short8 a0 = *(const short8*)((const char*)Ksb + lq * 128 +
                    ((st * 32 + hi * 16) ^ swq));
        short8 a1 = *(const short8*)((const char*)Ksb + (32 + lq) * 128 +
                    ((st * 32 + hi * 16) ^ swq));
        s0 = __builtin_amdgcn_mfma_f32_32x32x16_bf16(a0, qf[st], s0, 0, 0, 0);
        s1 = __builtin_amdgcn_mfma_f32_32x32x16_bf16(a1, qf[st], s1, 0, 0, 0);
      }
      __builtin_amdgcn_s_setprio(0);

      if (kt * 64 + 63 > qbase) {  // tile overlaps the diagonal for this wave
        int relk = qbase + lq - kt * 64;
#pragma unroll
        for (int r = 0; r < 16; ++r) {
          int km = (r & 3) + 8 * (r >> 2) + 4 * hi;  // C-row map (32x32)
          if (km > relk) s0[r] = -__builtin_inff();
          if (km + 32 > relk) s1[r] = -__builtin_inff();
        }
      }

      // tree max over 32 lane-local scores, then one cross-lane swap
      float t8[8];
#pragma unroll
      for (int r = 0; r < 8; ++r)
        t8[r] = fmaxf(fmaxf(s0[2 * r], s0[2 * r + 1]),
                      fmaxf(s1[2 * r], s1[2 * r + 1]));
      float mA = fmaxf(fmaxf(t8[0], t8[1]), fmaxf(t8[2], t8[3]));
      float mB = fmaxf(fmaxf(t8[4], t8[5]), fmaxf(t8[6], t8[7]));
      float mx = xor32max(fmaxf(mA, mB));

      // defer-max: rescale only if some lane's max grew past m+8 (T13)
      if (__any(mx > m + 8.0f)) {
        float nm = fmaxf(m, mx);
        float al = exp2fast(m - nm);
        m = nm;
        ls *= al;
        o0 *= al;
        o1 *= al;
      }
      float ps0 = 0.f, ps1 = 0.f, ps2 = 0.f, ps3 = 0.f;
#pragma unroll
      for (int r = 0; r < 16; ++r) {
        float p = exp2fast(s0[r] - m);
        s0[r] = p;
        if (r < 8) ps0 += p; else ps1 += p;
      }
#pragma unroll
      for (int r = 0; r < 16; ++r) {
        float p = exp2fast(s1[r] - m);
        s1[r] = p;
        if (r < 8) ps2 += p; else ps3 += p;
      }
      ls += (ps0 + ps1) + (ps2 + ps3);

      // P^T -> bf16 packs (pairs of consecutive k within own half)
      unsigned int pk0[8], pk1[8];
#pragma unroll
      for (int jp = 0; jp < 8; ++jp) {
        pk0[jp] = cvtpk(s0[2 * jp], s0[2 * jp + 1]);
        pk1[jp] = cvtpk(s1[2 * jp], s1[2 * jp + 1]);
      }
      __builtin_amdgcn_s_setprio(1);
#pragma unroll
      for (int ks = 0; ks < 4; ++ks) {
        const int off = 4 * (ks & 1);
        unsigned int a0 = (ks < 2) ? pk0[off + 0] : pk1[off + 0];
        unsigned int a1 = (ks < 2) ? pk0[off + 1] : pk1[off + 1];
        unsigned int b0 = (ks < 2) ? pk0[off + 2] : pk1[off + 2];
        unsigned int b1 = (ks < 2) ? pk0[off + 3] : pk1[off + 3];
        uint2v w0 = __builtin_amdgcn_permlane32_swap(a0, b0, false, false);
        uint2v w1 = __builtin_amdgcn_permlane32_swap(a1, b1, false, false);
        union { unsigned int u[4]; short8 s; } F;
        F.u[0] = w0[0]; F.u[1] = w1[0]; F.u[2] = w0[1]; F.u[3] = w1[1];
        short8 v0 = *(const short8*)((const char*)Vsb + lq * 128 +
                    ((ks * 32 + hi * 16) ^ swq));
        short8 v1 = *(const short8*)((const char*)Vsb + (32 + lq) * 128 +
                    ((ks * 32 + hi * 16) ^ swq));
        o0 = __builtin_amdgcn_mfma_f32_32x32x16_bf16(v0, F.s, o0, 0, 0, 0);
        o1 = __builtin_amdgcn_mfma_f32_32x32x16_bf16(v1, F.s, o1, 0, 0, 0);
      }
      __builtin_amdgcn_s_setprio(0);
    }
    if (kt + 1 < ktend) {  // write next tile into the other buffer
      *(short8*)((char*)Ks[cur ^ 1] + so0) = gK[0];
      *(short8*)((char*)Ks[cur ^ 1] + so0 + 32 * 128) = gK[1];
      *(short8*)((char*)Vs[cur ^ 1] + so0) = gV[0];
      *(short8*)((char*)Vs[cur ^ 1] + so0 + 32 * 128) = gV[1];
    }
    __syncthreads();
  }

  // partial store: m, ls (uniform across lane pairs) + raw O^T as bf16
  ls = xor32add(ls);
  if (hi == 0) {
    float* mlsJ = mls + (size_t)(((half * 32 + hb) * 16 + qt) * 2) * 128;
    mlsJ[w * 32 + lq] = m;
    mlsJ[128 + w * 32 + lq] = ls;
  }
  unsigned short* P = (half ? P1 : P0) + (size_t)(hb * 16 + qt) * 128 * 64;
  char* Osw = (char*)Ks + w * 4096;
#pragma unroll
  for (int jp = 0; jp < 8; ++jp) {
    const int r = 2 * jp;
    const int km = (r & 3) + 8 * (r >> 2) + 4 * hi;  // even
    unsigned int pa = cvtpk(o0[r], o0[r + 1]);
    unsigned int pb = cvtpk(o1[r], o1[r + 1]);
    *(unsigned int*)(Osw + lq * 128 + ((2 * km) ^ swq)) = pa;
    *(unsigned int*)(Osw + lq * 128 + ((2 * (km + 32)) ^ swq)) = pb;
  }
  __builtin_amdgcn_wave_barrier();
#pragma unroll
  for (int pass = 0; pass < 4; ++pass) {
    int q2 = pass * 8 + (lane >> 3);
    int c16 = (lane & 7) * 16;
    short8 vrow = *(const short8*)(Osw + q2 * 128 + (c16 ^ ((q2 & 7) << 4)));
    *(short8*)(P + (size_t)(w * 32 + q2) * 64 + (lane & 7) * 8) = vrow;
  }
}

// ---------------- combine: merge the two k-half partials ----------------

__global__ __launch_bounds__(256) void combine_kernel(
    const unsigned short* __restrict__ P0, const unsigned short* __restrict__ P1,
    const float* __restrict__ mls, unsigned short* __restrict__ Obf) {
  const int qt = blockIdx.x, hb = blockIdx.y;
  const int t = threadIdx.x;
  const int q = t >> 1, dh = (t & 1) * 32;
  const float* m0p = mls + (size_t)(((0 * 32 + hb) * 16 + qt) * 2) * 128;
  const float* m1p = mls + (size_t)(((1 * 32 + hb) * 16 + qt) * 2) * 128;
  float m0 = m0p[q], ls0 = m0p[128 + q];
  float m1 = m1p[q], ls1 = m1p[128 + q];
  float M = fmaxf(m0, m1);
  float w0 = exp2fast(m0 - M), w1 = exp2fast(m1 - M);
  float inv = 1.0f / (ls0 * w0 + ls1 * w1);
  float f0 = w0 * inv, f1 = w1 * inv;
  size_t rowoff = ((size_t)(hb * 16 + qt) * 128 + q) * 64 + dh;
  int b = hb & 1, h = hb >> 1;
  unsigned short* dst = Obf + ((size_t)(b * 2048 + qt * 128 + q)) * 1024 + h * 64 + dh;
#pragma unroll
  for (int c = 0; c < 32; c += 8) {
    union { short8 s; unsigned short u[8]; } a, bb, o;
    a.s = *(const short8*)(P0 + rowoff + c);
    bb.s = *(const short8*)(P1 + rowoff + c);
#pragma unroll
    for (int e = 0; e < 8; ++e) {
      float p0 = __uint_as_float((unsigned)a.u[e] << 16);
      float p1 = __uint_as_float((unsigned)bb.u[e] << 16);
      o.u[e] = f2b(p0 * f0 + p1 * f1);
    }
    *(short8*)(dst + c) = o.s;
  }
}

// ---------------- launch ----------------

extern "C" void kernel_launch(void* const* d_in, const int* in_sizes, int n_in,
                              void* d_out, int out_size, void* d_ws, size_t ws_size,
                              hipStream_t stream) {
  const float* x  = (const float*)d_in[0];
  const float* wq = (const float*)d_in[1];
  const float* wk = (const float*)d_in[2];
  const float* wv = (const float*)d_in[3];
  const float* wo = (const float*)d_in[4];
  float* out = (float*)d_out;

  char* ws = (char*)d_ws;
  const size_t SZ = 8388608;  // 8 MiB
  unsigned short* xb  = (unsigned short*)(ws);            // x bf16; later: P1 partials
  unsigned short* wT  = (unsigned short*)(ws + SZ);       // 4 x 2MiB (q,k,v,o)
  unsigned short* Qb  = (unsigned short*)(ws + 2 * SZ);   // Q; later: combined O (Obf)
  unsigned short* Kb  = (unsigned short*)(ws + 3 * SZ);
  unsigned short* VTb = (unsigned short*)(ws + 4 * SZ);
  unsigned short* P0  = (unsigned short*)(ws + 5 * SZ);   // half0 partials
  float* ctab = (float*)(ws + 6 * SZ);                    // rope tables; later: mls
  float* stab = ctab + 65536;
  float* mls  = ctab;                                     // overlays dead tables
  if (ws_size < 6 * SZ + 1048576) return;  // ws too small: fail loudly (zeros)

  unsigned short* P1  = xb;
  unsigned short* Obf = Qb;

  prep_kernel<<<8448, 256, 0, stream>>>(x, wq, wk, wv, wo, xb, wT, ctab, stab);
  gemm_kernel<<<dim3(32, 8, 3), 256, 0, stream>>>(xb, wT, Qb, Kb, VTb, ctab, stab);
  attn_kernel<<<dim3(32, 32), 256, 0, stream>>>(Qb, Kb, VTb, P0, P1, mls);
  combine_kernel<<<dim3(16, 32), 256, 0, stream>>>(P0, P1, mls, Obf);
  gemm_final_kernel<<<dim3(64, 8), 128, 0, stream>>>(Obf, wT + 3 * 1048576, out);
}

// Round 12
// 132.738 us; speedup vs baseline: 1.1267x; 1.1267x over previous
//
#include <hip/hip_runtime.h>
#include <stdint.h>

typedef __attribute__((ext_vector_type(8))) short short8;
typedef __attribute__((ext_vector_type(4))) float f32x4;
typedef __attribute__((ext_vector_type(4))) unsigned short ushort4v;
typedef __attribute__((ext_vector_type(2))) unsigned int uint2v;

static __device__ __forceinline__ unsigned short f2b(float f) {
  union { float f; unsigned int u; } v; v.f = f;
  unsigned int r = v.u + 0x7FFFu + ((v.u >> 16) & 1u);
  return (unsigned short)(r >> 16);
}

static __device__ __forceinline__ float exp2fast(float x) {
#if __has_builtin(__builtin_amdgcn_exp2f)
  return __builtin_amdgcn_exp2f(x);
#else
  return exp2f(x);
#endif
}

static __device__ __forceinline__ unsigned int cvtpk(float lo, float hi) {
  unsigned int r;
  asm("v_cvt_pk_bf16_f32 %0, %1, %2" : "=v"(r) : "v"(lo), "v"(hi));
  return r;
}

// Cross-lane ^16 / ^32 reduces via permlane*_swap (VALU) - verified r5/r6.
static __device__ __forceinline__ float xor16max(float x) {
#if __has_builtin(__builtin_amdgcn_permlane16_swap)
  unsigned u = __float_as_uint(x);
  uint2v r = __builtin_amdgcn_permlane16_swap(u, u, false, false);
  return fmaxf(__uint_as_float(r[0]), __uint_as_float(r[1]));
#else
  return fmaxf(x, __shfl_xor(x, 16));
#endif
}
static __device__ __forceinline__ float xor32max(float x) {
#if __has_builtin(__builtin_amdgcn_permlane32_swap)
  unsigned u = __float_as_uint(x);
  uint2v r = __builtin_amdgcn_permlane32_swap(u, u, false, false);
  return fmaxf(__uint_as_float(r[0]), __uint_as_float(r[1]));
#else
  return fmaxf(x, __shfl_xor(x, 32));
#endif
}
static __device__ __forceinline__ float xor16add(float x) {
#if __has_builtin(__builtin_amdgcn_permlane16_swap)
  unsigned u = __float_as_uint(x);
  uint2v r = __builtin_amdgcn_permlane16_swap(u, u, false, false);
  return __uint_as_float(r[0]) + __uint_as_float(r[1]);
#else
  return x + __shfl_xor(x, 16);
#endif
}
static __device__ __forceinline__ float xor32add(float x) {
#if __has_builtin(__builtin_amdgcn_permlane32_swap)
  unsigned u = __float_as_uint(x);
  uint2v r = __builtin_amdgcn_permlane32_swap(u, u, false, false);
  return __uint_as_float(r[0]) + __uint_as_float(r[1]);
#else
  return x + __shfl_xor(x, 32);
#endif
}

static __device__ __forceinline__ void gload16(const void* g, void* l) {
  __builtin_amdgcn_global_load_lds(
      (const __attribute__((address_space(1))) unsigned int*)g,
      (__attribute__((address_space(3))) unsigned int*)l, 16, 0, 0);
}

// ---------------- fused prep: cast_x | weight transpose | rope tables ----------------

__global__ __launch_bounds__(256) void prep_kernel(
    const float* __restrict__ x, const float* __restrict__ wq,
    const float* __restrict__ wk, const float* __restrict__ wv,
    const float* __restrict__ wo, unsigned short* __restrict__ xb,
    unsigned short* __restrict__ wT, float* __restrict__ ct,
    float* __restrict__ st) {
  __shared__ float t[32][33];
  const int bid = blockIdx.x, tid = threadIdx.x;
  if (bid < 4096) {  // cast x -> bf16
    int i = (bid * 256 + tid) * 4;
    float4 v = *(const float4*)(x + i);
    ushort4v o = { f2b(v.x), f2b(v.y), f2b(v.z), f2b(v.w) };
    *(ushort4v*)(xb + i) = o;
  } else if (bid < 8192) {  // transpose+cast weights
    int tt = bid - 4096;
    int z = tt >> 10, xy = tt & 1023;
    const float* src = (z == 0) ? wq : (z == 1) ? wk : (z == 2) ? wv : wo;
    unsigned short* dst = wT + (size_t)z * 1048576;
    int tx = tid & 31, ty = tid >> 5;
    int n0 = (xy & 31) * 32, k0 = (xy >> 5) * 32;
#pragma unroll
    for (int i = 0; i < 4; ++i) {
      int r = ty + i * 8;
      t[r][tx] = src[(size_t)(k0 + r) * 1024 + n0 + tx];
    }
    __syncthreads();
#pragma unroll
    for (int i = 0; i < 4; ++i) {
      int r = ty + i * 8;
      dst[(size_t)(n0 + r) * 1024 + k0 + tx] = f2b(t[tx][r]);
    }
  } else {  // rope tables (2048*32 entries)
    int i = (bid - 8192) * 256 + tid;
    int s = i >> 5, p = i & 31;
    float ang = (float)s * powf(10000.0f, -(float)(2 * p) / 64.0f);
    ct[i] = cosf(ang);
    st[i] = sinf(ang);
  }
}

// ---------------- QKV GEMM: 128x128 tile, K-step 64 via two BK=32 LDS panels --------
// Identical LDS layout / fragment reads to the proven m97-style code, but ONE
// barrier pair per 64 of K (vmcnt+barrier drain count halved -- the known 2-phase
// stall, m233). mode 0: Q epilogue (RoPE + 0.125*log2e); 1: K; 2: V transposed.

__global__ __launch_bounds__(256) void gemm_kernel(
    const unsigned short* __restrict__ A, const unsigned short* __restrict__ WT,
    unsigned short* __restrict__ Qb, unsigned short* __restrict__ Kb,
    unsigned short* __restrict__ VTb,
    const float* __restrict__ ctab, const float* __restrict__ stab) {
  __shared__ unsigned short As[2][128 * 32];
  __shared__ unsigned short Bs[2][128 * 32];
  const int tid = threadIdx.x;
  const int w = tid >> 6, lane = tid & 63;
  const int m0 = blockIdx.x * 128, n0 = blockIdx.y * 128;
  const int mode = blockIdx.z;
  const unsigned short* Bt = WT + (size_t)mode * 1048576;
  const int wr = w >> 1, wc = w & 1;
  const int srow = lane >> 2, scol = lane & 3;
  f32x4 acc[4][4] = {};
  for (int k0 = 0; k0 < 1024; k0 += 64) {
#pragma unroll
    for (int p = 0; p < 2; ++p)
#pragma unroll
      for (int c = 0; c < 2; ++c) {
        int chunk = w * 2 + c;
        gload16(A + (size_t)(m0 + chunk * 16 + srow) * 1024 + k0 + p * 32 + scol * 8,
                (char*)As[p] + chunk * 1024);
        gload16(Bt + (size_t)(n0 + chunk * 16 + srow) * 1024 + k0 + p * 32 + scol * 8,
                (char*)Bs[p] + chunk * 1024);
      }
    __syncthreads();
#pragma unroll
    for (int p = 0; p < 2; ++p) {
      short8 af[4], bf[4];
#pragma unroll
      for (int i = 0; i < 4; ++i) {
        af[i] = *(const short8*)((const char*)As[p] +
                ((wr * 64 + i * 16 + (lane & 15)) * 64 + (lane >> 4) * 16));
        bf[i] = *(const short8*)((const char*)Bs[p] +
                ((wc * 64 + i * 16 + (lane & 15)) * 64 + (lane >> 4) * 16));
      }
#pragma unroll
      for (int i = 0; i < 4; ++i)
#pragma unroll
        for (int j = 0; j < 4; ++j)
          acc[i][j] = __builtin_amdgcn_mfma_f32_16x16x32_bf16(af[i], bf[j], acc[i][j], 0, 0, 0);
    }
    __syncthreads();
  }

  if (mode < 2) {
    unsigned short* dst = mode ? Kb : Qb;
    const float qscale = mode ? 1.0f : 0.125f * 1.44269504088896f;
#pragma unroll
    for (int i = 0; i < 4; ++i) {
#pragma unroll
      for (int j = 0; j < 4; ++j) {
        int n = n0 + wc * 64 + j * 16 + (lane & 15);
        int h = n >> 6, d = n & 63;
        int pairIdx = d >> 1;
        bool even = (n & 1) == 0;
#pragma unroll
        for (int r = 0; r < 4; ++r) {
          int m = m0 + wr * 64 + i * 16 + (lane >> 4) * 4 + r;
          int b = m >> 11, s = m & 2047;
          float v = acc[i][j][r];
          float pv = __shfl_xor(v, 1);
          float c = ctab[s * 32 + pairIdx], sn = stab[s * 32 + pairIdx];
          float ov = (even ? (v * c - pv * sn) : (pv * sn + v * c)) * qscale;
          dst[(size_t)((h * 2 + b) * 2048 + s) * 64 + d] = f2b(ov);
        }
      }
    }
  } else {
#pragma unroll
    for (int i = 0; i < 4; ++i) {
#pragma unroll
      for (int j = 0; j < 4; ++j) {
        int n = n0 + wc * 64 + j * 16 + (lane & 15);
        int h = n >> 6, d = n & 63;
        int mBase = m0 + wr * 64 + i * 16 + (lane >> 4) * 4;
        int b = mBase >> 11, s = mBase & 2047;
        ushort4v pk = { f2b(acc[i][j][0]), f2b(acc[i][j][1]),
                        f2b(acc[i][j][2]), f2b(acc[i][j][3]) };
        *(ushort4v*)(VTb + (size_t)((h * 2 + b) * 64 + d) * 2048 + s) = pk;
      }
    }
  }
}

// ---------------- final GEMM: 64x128 tile, 2-wave blocks, fp32 out ----------------

__global__ __launch_bounds__(128) void gemm_final_kernel(
    const unsigned short* __restrict__ A, const unsigned short* __restrict__ Bt,
    float* __restrict__ Fout) {
  __shared__ unsigned short As[64 * 32];
  __shared__ unsigned short Bs[128 * 32];
  const int tid = threadIdx.x;
  const int w = tid >> 6, lane = tid & 63;
  const int m0 = blockIdx.x * 64, n0 = blockIdx.y * 128;
  const int srow = lane >> 2, scol = lane & 3;
  f32x4 acc[4][4] = {};
  for (int k0 = 0; k0 < 1024; k0 += 32) {
#pragma unroll
    for (int c = 0; c < 2; ++c) {
      int chunk = w * 2 + c;
      gload16(A + (size_t)(m0 + chunk * 16 + srow) * 1024 + k0 + scol * 8,
              (char*)As + chunk * 1024);
    }
#pragma unroll
    for (int c = 0; c < 4; ++c) {
      int chunk = w * 4 + c;
      gload16(Bt + (size_t)(n0 + chunk * 16 + srow) * 1024 + k0 + scol * 8,
              (char*)Bs + chunk * 1024);
    }
    __syncthreads();
    short8 af[4], bf[4];
#pragma unroll
    for (int i = 0; i < 4; ++i) {
      af[i] = *(const short8*)((const char*)As +
              ((i * 16 + (lane & 15)) * 64 + (lane >> 4) * 16));
      bf[i] = *(const short8*)((const char*)Bs +
              ((w * 64 + i * 16 + (lane & 15)) * 64 + (lane >> 4) * 16));
    }
#pragma unroll
    for (int i = 0; i < 4; ++i)
#pragma unroll
      for (int j = 0; j < 4; ++j)
        acc[i][j] = __builtin_amdgcn_mfma_f32_16x16x32_bf16(af[i], bf[j], acc[i][j], 0, 0, 0);
    __syncthreads();
  }
#pragma unroll
  for (int i = 0; i < 4; ++i)
#pragma unroll
    for (int j = 0; j < 4; ++j) {
      int n = n0 + w * 64 + j * 16 + (lane & 15);
#pragma unroll
      for (int r = 0; r < 4; ++r) {
        int m = m0 + i * 16 + (lane >> 4) * 4 + r;
        Fout[(size_t)m * 1024 + n] = acc[i][j][r];
      }
    }
}

// ---------------- causal flash attention (r6-exact: best measured, 52.9 us) ---------
// Pair-balanced blocks (qtL=bx, qtH=31-bx). Swapped-QK: S^T = mfma(K,Q); lane
// owns q=lane&15, k-rows 16ct+4lh+r. Lane-local softmax + permlane reduces;
// deferred l-sum; P via b64-write/b128-read LDS roundtrip; dbuf K/V staging.

__device__ __forceinline__ void proc_tile(
    const short8 aq[2], const unsigned short* Ksb, const unsigned short* Vsb,
    char* Psw, int lq, int lh, int wq16, bool diag,
    float& m, float& ls, f32x4* o) {
  const int swq = (lq & 7) << 4;
  f32x4 sacc[4] = {};
  __builtin_amdgcn_s_setprio(1);
#pragma unroll
  for (int ct = 0; ct < 4; ++ct) {
    const char* base = (const char*)Ksb + (ct * 16 + lq) * 128;
#pragma unroll
    for (int half = 0; half < 2; ++half) {
      short8 ak = *(const short8*)(base + ((half * 64 + lh * 16) ^ swq));
      sacc[ct] = __builtin_amdgcn_mfma_f32_16x16x32_bf16(ak, aq[half], sacc[ct], 0, 0, 0);
    }
  }
  __builtin_amdgcn_s_setprio(0);

  if (diag) {  // mask if k_local = 16ct + 4lh + r > q_local = wq16 + lq
    int rel = wq16 + lq - 4 * lh;
#pragma unroll
    for (int ct = 0; ct < 4; ++ct)
#pragma unroll
      for (int r = 0; r < 4; ++r)
        if (ct * 16 + r > rel) sacc[ct][r] = -__builtin_inff();
  }

  float mx0 = fmaxf(fmaxf(sacc[0][0], sacc[0][1]), fmaxf(sacc[0][2], sacc[0][3]));
  float mx1 = fmaxf(fmaxf(sacc[1][0], sacc[1][1]), fmaxf(sacc[1][2], sacc[1][3]));
  float mx2 = fmaxf(fmaxf(sacc[2][0], sacc[2][1]), fmaxf(sacc[2][2], sacc[2][3]));
  float mx3 = fmaxf(fmaxf(sacc[3][0], sacc[3][1]), fmaxf(sacc[3][2], sacc[3][3]));
  float mx = fmaxf(fmaxf(mx0, mx1), fmaxf(mx2, mx3));
  mx = xor16max(mx);
  mx = xor32max(mx);
  float nm = fmaxf(m, mx);
  float al = exp2fast(m - nm);
  m = nm;
  float ps = 0.f;
#pragma unroll
  for (int ct = 0; ct < 4; ++ct)
#pragma unroll
    for (int r = 0; r < 4; ++r) {
      float p = exp2fast(sacc[ct][r] - nm);
      sacc[ct][r] = p;
      ps += p;
    }
  ls = ls * al + ps;  // per-lane partial; cross-lane reduce deferred to epilogue
#pragma unroll
  for (int ct = 0; ct < 4; ++ct)
#pragma unroll
    for (int r = 0; r < 4; ++r) o[ct][r] *= al;

  // P[q=lq][k=16ct+4lh+{0..3}] -> one b64 write per ct (4 contiguous k)
#pragma unroll
  for (int ct = 0; ct < 4; ++ct) {
    uint2v pk = { cvtpk(sacc[ct][0], sacc[ct][1]), cvtpk(sacc[ct][2], sacc[ct][3]) };
    *(uint2v*)(Psw + lq * 128 + ((ct * 32 + lh * 8) ^ swq)) = pk;
  }
  __builtin_amdgcn_wave_barrier();
  short8 pa[2];
#pragma unroll
  for (int half = 0; half < 2; ++half)
    pa[half] = *(const short8*)(Psw + lq * 128 + ((half * 64 + lh * 16) ^ swq));

  __builtin_amdgcn_s_setprio(1);
#pragma unroll
  for (int ct = 0; ct < 4; ++ct) {
    const char* base = (const char*)Vsb + (ct * 16 + lq) * 128;
#pragma unroll
    for (int half = 0; half < 2; ++half) {
      short8 av = *(const short8*)(base + ((half * 64 + lh * 16) ^ swq));
      o[ct] = __builtin_amdgcn_mfma_f32_16x16x32_bf16(av, pa[half], o[ct], 0, 0, 0);
    }
  }
  __builtin_amdgcn_s_setprio(0);
}

__device__ __forceinline__ void store_o(
    const f32x4* o, float ls, char* Psw, unsigned short* __restrict__ Ob,
    int lane, int lq, int lh, int w, int qb, int h, int b) {
  float l = xor32add(xor16add(ls));  // deferred l reduction
  float invl = 1.0f / l;
#pragma unroll
  for (int ct = 0; ct < 4; ++ct)
#pragma unroll
    for (int r = 0; r < 4; ++r) {
      int d = ct * 16 + lh * 4 + r;
      *(unsigned short*)(Psw + lq * 128 + ((2 * d) ^ ((lq & 7) << 4))) =
          f2b(o[ct][r] * invl);
    }
  __builtin_amdgcn_wave_barrier();  // Psw is wave-private
#pragma unroll
  for (int pass = 0; pass < 2; ++pass) {
    int q2 = pass * 8 + (lane >> 3), d0 = (lane & 7) * 8;
    short8 vrow = *(const short8*)(Psw + q2 * 128 + ((2 * d0) ^ ((q2 & 7) << 4)));
    int s = qb + w * 16 + q2;
    *(short8*)(Ob + ((size_t)(b * 2048 + s)) * 1024 + h * 64 + d0) = vrow;
  }
  __builtin_amdgcn_wave_barrier();
}

__global__ __launch_bounds__(256) void attn_kernel(
    const unsigned short* __restrict__ Qb, const unsigned short* __restrict__ Kb,
    const unsigned short* __restrict__ VTb, unsigned short* __restrict__ Ob) {
  __shared__ unsigned short Ks[2][64 * 64];
  __shared__ unsigned short Vs[2][64 * 64];
  __shared__ unsigned short Ps[4 * 16 * 64];
  const int tid = threadIdx.x, w = tid >> 6, lane = tid & 63;
  const int qtL = blockIdx.x, qtH = 31 - blockIdx.x;
  const int hb = blockIdx.y;
  const int h = hb >> 1, b = hb & 1;
  const unsigned short* Qhb = Qb + (size_t)hb * 2048 * 64;
  const unsigned short* Khb = Kb + (size_t)hb * 2048 * 64;
  const unsigned short* Vhb = VTb + (size_t)hb * 64 * 2048;
  char* Psw = (char*)Ps + w * 2048;
  const int lq = lane & 15, lh = lane >> 4;
  const int wq16 = w * 16;

  short8 aqL[2], aqH[2];
  {
    int rowL = qtL * 64 + wq16 + lq;
    int rowH = qtH * 64 + wq16 + lq;
#pragma unroll
    for (int half = 0; half < 2; ++half) {
      aqL[half] = *(const short8*)(Qhb + (size_t)rowL * 64 + half * 32 + lh * 8);
      aqH[half] = *(const short8*)(Qhb + (size_t)rowH * 64 + half * 32 + lh * 8);
    }
  }
  float mL = -__builtin_inff(), lsL = 0.f;
  float mH = -__builtin_inff(), lsH = 0.f;
  f32x4 oL[4] = {}, oH[4] = {};

  // staging: thread owns rows r0, r0+32 (16B each)
  const int r0 = tid >> 3, f0 = tid & 7;
  const int so0 = r0 * 128 + ((f0 * 16) ^ ((r0 & 7) << 4));
  short8 gK[2], gV[2];
  gK[0] = *(const short8*)(Khb + (size_t)r0 * 64 + f0 * 8);
  gK[1] = *(const short8*)(Khb + (size_t)(r0 + 32) * 64 + f0 * 8);
  gV[0] = *(const short8*)(Vhb + (size_t)r0 * 2048 + f0 * 8);
  gV[1] = *(const short8*)(Vhb + (size_t)(r0 + 32) * 2048 + f0 * 8);
  *(short8*)((char*)Ks[0] + so0) = gK[0];
  *(short8*)((char*)Ks[0] + so0 + 32 * 128) = gK[1];
  *(short8*)((char*)Vs[0] + so0) = gV[0];
  *(short8*)((char*)Vs[0] + so0 + 32 * 128) = gV[1];
  __syncthreads();

  for (int kt = 0; kt <= qtH; ++kt) {
    const int cur = kt & 1;
    if (kt < qtH) {  // issue next tile's loads; latency hides under compute
      int kk0 = (kt + 1) * 64;
      gK[0] = *(const short8*)(Khb + (size_t)(kk0 + r0) * 64 + f0 * 8);
      gK[1] = *(const short8*)(Khb + (size_t)(kk0 + r0 + 32) * 64 + f0 * 8);
      gV[0] = *(const short8*)(Vhb + (size_t)r0 * 2048 + kk0 + f0 * 8);
      gV[1] = *(const short8*)(Vhb + (size_t)(r0 + 32) * 2048 + kk0 + f0 * 8);
    }
    proc_tile(aqH, Ks[cur], Vs[cur], Psw, lq, lh, wq16, kt == qtH, mH, lsH, oH);
    if (kt <= qtL)
      proc_tile(aqL, Ks[cur], Vs[cur], Psw, lq, lh, wq16, kt == qtL, mL, lsL, oL);
    if (kt < qtH) {  // write next tile into the other buffer
      *(short8*)((char*)Ks[cur ^ 1] + so0) = gK[0];
      *(short8*)((char*)Ks[cur ^ 1] + so0 + 32 * 128) = gK[1];
      *(short8*)((char*)Vs[cur ^ 1] + so0) = gV[0];
      *(short8*)((char*)Vs[cur ^ 1] + so0 + 32 * 128) = gV[1];
    }
    __syncthreads();
  }

  store_o(oL, lsL, Psw, Ob, lane, lq, lh, w, qtL * 64, h, b);
  store_o(oH, lsH, Psw, Ob, lane, lq, lh, w, qtH * 64, h, b);
}

// ---------------- launch ----------------

extern "C" void kernel_launch(void* const* d_in, const int* in_sizes, int n_in,
                              void* d_out, int out_size, void* d_ws, size_t ws_size,
                              hipStream_t stream) {
  const float* x  = (const float*)d_in[0];
  const float* wq = (const float*)d_in[1];
  const float* wk = (const float*)d_in[2];
  const float* wv = (const float*)d_in[3];
  const float* wo = (const float*)d_in[4];
  float* out = (float*)d_out;

  char* ws = (char*)d_ws;
  const size_t SZ = 8388608;  // 8 MiB
  unsigned short* xb  = (unsigned short*)(ws);
  unsigned short* wT  = (unsigned short*)(ws + SZ);       // 4 x 2MiB (q,k,v,o)
  unsigned short* Qb  = (unsigned short*)(ws + 2 * SZ);
  unsigned short* Kb  = (unsigned short*)(ws + 3 * SZ);
  unsigned short* VTb = (unsigned short*)(ws + 4 * SZ);
  unsigned short* Ob  = (unsigned short*)(ws + 5 * SZ);
  float* ctab = (float*)(ws + 6 * SZ);
  float* stab = (float*)(ws + 6 * SZ + 262144);
  if (ws_size < 6 * SZ + 2 * 262144) return;  // ws too small: fail loudly (zeros)

  prep_kernel<<<8448, 256, 0, stream>>>(x, wq, wk, wv, wo, xb, wT, ctab, stab);
  gemm_kernel<<<dim3(32, 8, 3), 256, 0, stream>>>(xb, wT, Qb, Kb, VTb, ctab, stab);
  attn_kernel<<<dim3(16, 32), 256, 0, stream>>>(Qb, Kb, VTb, Ob);
  gemm_final_kernel<<<dim3(64, 8), 128, 0, stream>>>(Ob, wT + 3 * 1048576, out);
}